// Round 3
// baseline (452.772 us; speedup 1.0000x reference)
//
#include <hip/hip_runtime.h>
#include <math.h>

// Problem constants (B=4, N=1024, D=1024, H=2048, E=8)
#define T_TOK 4096
#define DIM   1024
#define HID   2048
#define NE    8
#define TM    128   // M/N tile for MFMA GEMMs
#define BK    64    // K chunk (bf16)

typedef unsigned int  u32;
typedef unsigned short u16;
typedef __attribute__((ext_vector_type(8))) short bf16x8;   // 8 bf16 in 4 VGPRs
typedef __attribute__((ext_vector_type(16))) float f32x16;  // 32x32 acc

__device__ __forceinline__ float gelu_exact(float v) {
    return 0.5f * v * (1.0f + erff(v * 0.70710678118654752440f));
}

__device__ __forceinline__ u16 f2bf(float v) {
    u32 u = __float_as_uint(v);
    u32 r = (u + 0x7FFFu + ((u >> 16) & 1u)) >> 16;   // RNE
    return (u16)r;
}

// async global->LDS, 16B per lane; lds dest = wave-uniform base + lane*16
__device__ __forceinline__ void gld_lds16(const void* g, void* l) {
    __builtin_amdgcn_global_load_lds(
        (const __attribute__((address_space(1))) u32*)g,
        (__attribute__((address_space(3))) u32*)l,
        16, 0, 0);
}

// ---------------------------------------------------------------------------
// Gate: logits = x @ gate_w + gate_b ; softmax ; top-1 ; importance sums
// ---------------------------------------------------------------------------
__global__ __launch_bounds__(256) void gate_kernel(
    const float* __restrict__ x, const float* __restrict__ gw,
    const float* __restrict__ gb, float* __restrict__ top_val,
    int* __restrict__ top_idx, float* __restrict__ importance,
    int* __restrict__ counts)
{
    __shared__ float s_imp[NE];
    __shared__ int   s_cnt[NE];
    if (threadIdx.x < NE) { s_imp[threadIdx.x] = 0.f; s_cnt[threadIdx.x] = 0; }
    __syncthreads();

    const int wave = threadIdx.x >> 6;
    const int lane = threadIdx.x & 63;
    const int t = blockIdx.x * 4 + wave;

    float acc[NE];
    #pragma unroll
    for (int e = 0; e < NE; e++) acc[e] = 0.f;

    const float* xr = x + (size_t)t * DIM;
    #pragma unroll 4
    for (int k = lane; k < DIM; k += 64) {
        float xv = xr[k];
        const float* g = gw + (size_t)k * NE;
        float4 g0 = *(const float4*)g;
        float4 g1 = *(const float4*)(g + 4);
        acc[0] += xv * g0.x; acc[1] += xv * g0.y;
        acc[2] += xv * g0.z; acc[3] += xv * g0.w;
        acc[4] += xv * g1.x; acc[5] += xv * g1.y;
        acc[6] += xv * g1.z; acc[7] += xv * g1.w;
    }
    #pragma unroll
    for (int e = 0; e < NE; e++) {
        #pragma unroll
        for (int off = 32; off > 0; off >>= 1)
            acc[e] += __shfl_down(acc[e], off, 64);
    }
    if (lane == 0) {
        float l[NE];
        float m = -1e30f;
        #pragma unroll
        for (int e = 0; e < NE; e++) { l[e] = acc[e] + gb[e]; m = fmaxf(m, l[e]); }
        float s = 0.f;
        #pragma unroll
        for (int e = 0; e < NE; e++) { l[e] = expf(l[e] - m); s += l[e]; }
        float inv = 1.f / s;
        int bi = 0; float bv = -1.f;
        #pragma unroll
        for (int e = 0; e < NE; e++) {
            float p = l[e] * inv;
            atomicAdd(&s_imp[e], p);
            if (p > bv) { bv = p; bi = e; }
        }
        top_val[t] = bv;
        top_idx[t] = bi;
        atomicAdd(&s_cnt[bi], 1);
    }
    __syncthreads();
    if (threadIdx.x < NE) {
        atomicAdd(&importance[threadIdx.x], s_imp[threadIdx.x]);
        atomicAdd(&counts[threadIdx.x],     s_cnt[threadIdx.x]);
    }
}

// ---------------------------------------------------------------------------
// Plan: expert offsets, 128-row tile table, load-balance loss.
// ---------------------------------------------------------------------------
__global__ void plan_kernel(const int* __restrict__ counts,
                            const float* __restrict__ importance,
                            int* __restrict__ offsets, int* __restrict__ tile_e,
                            int* __restrict__ tile_s, int* __restrict__ tile_rows,
                            int* __restrict__ ntiles, float* __restrict__ loss_out)
{
    if (threadIdx.x == 0 && blockIdx.x == 0) {
        int off = 0, nt = 0;
        for (int e = 0; e < NE; e++) {
            offsets[e] = off;
            int c = counts[e];
            for (int s = 0; s < c; s += TM) {
                tile_e[nt] = e;
                tile_s[nt] = off + s;
                tile_rows[nt] = min(TM, c - s);
                nt++;
            }
            off += c;
        }
        offsets[NE] = off;
        *ntiles = nt;   // <= 4096/128 + 8 = 40

        float mean = 0.f;
        for (int e = 0; e < NE; e++) mean += importance[e];
        mean *= (1.0f / NE);
        float var = 0.f;
        for (int e = 0; e < NE; e++) { float d = importance[e] - mean; var += d * d; }
        var *= (1.0f / (NE - 1));
        loss_out[0] = var / (mean * mean + 1e-10f);
    }
}

// ---------------------------------------------------------------------------
// Scatter: sorted token list per expert.
// ---------------------------------------------------------------------------
__global__ void scatter_kernel(const int* __restrict__ top_idx,
                               const int* __restrict__ offsets,
                               int* __restrict__ cursors,
                               int* __restrict__ sorted_tok)
{
    int t = blockIdx.x * blockDim.x + threadIdx.x;
    if (t < T_TOK) {
        int e = top_idx[t];
        int pos = atomicAdd(&cursors[e], 1);
        sorted_tok[offsets[e] + pos] = t;
    }
}

// ---------------------------------------------------------------------------
// Gather x rows into sorted order, fp32 -> bf16. One block per sorted row.
// ---------------------------------------------------------------------------
__global__ __launch_bounds__(256) void gather_x_kernel(
    const float* __restrict__ x, const int* __restrict__ sorted_tok,
    u16* __restrict__ xs)
{
    const int s = blockIdx.x;
    const int tok = sorted_tok[s];
    const float* src = x + (size_t)tok * DIM;
    u16* dst = xs + (size_t)s * DIM;
    const int i = threadIdx.x * 4;
    float4 v = *(const float4*)&src[i];
    ushort4 o;
    o.x = f2bf(v.x); o.y = f2bf(v.y); o.z = f2bf(v.z); o.w = f2bf(v.w);
    *(ushort4*)&dst[i] = o;
}

// ---------------------------------------------------------------------------
// Transpose + convert: in [E][R][C] f32  ->  out [E][C][R] bf16
// grid (C/32, R/32, E), block 256.
// ---------------------------------------------------------------------------
__global__ __launch_bounds__(256) void transpose_bf16_kernel(
    const float* __restrict__ in, u16* __restrict__ out, int R, int C)
{
    __shared__ float tile[32][33];
    const float* src = in  + (size_t)blockIdx.z * R * C;
    u16*         dst = out + (size_t)blockIdx.z * R * C;
    const int c0 = blockIdx.x * 32, r0 = blockIdx.y * 32;
    const int tc = threadIdx.x & 31, tr = threadIdx.x >> 5;  // tr in 0..7
    #pragma unroll
    for (int i = 0; i < 4; i++) {
        int r = tr + i * 8;
        tile[r][tc] = src[(size_t)(r0 + r) * C + c0 + tc];
    }
    __syncthreads();
    #pragma unroll
    for (int i = 0; i < 4; i++) {
        int cc = tr + i * 8;      // output row = c0+cc
        float v = tile[tc][cc];   // stride-33 read: conflict-free
        dst[(size_t)(c0 + cc) * R + r0 + tc] = f2bf(v);
    }
}

// ---------------------------------------------------------------------------
// FFN1 (MFMA 32x32x16, double-buffered): h = gelu(Xs @ W1t^T + b1), bf16 out.
// Xs: [4096][DIM] bf16 (sorted). W1t: [E][HID][DIM] bf16. h: [4096][HID] bf16.
// Block: 128x128 tile, 4 waves in 2x2, wave tile 64x64 = 2x2 accs of 32x32.
// ---------------------------------------------------------------------------
__global__ __launch_bounds__(256) void ffn1_mfma(
    const u16* __restrict__ xs, const u16* __restrict__ w1t,
    const float* __restrict__ b1,
    const int* __restrict__ tile_e, const int* __restrict__ tile_s,
    const int* __restrict__ tile_rows, const int* __restrict__ ntiles,
    u16* __restrict__ h_buf)
{
    const int tile = blockIdx.x;
    if (tile >= *ntiles) return;
    const int e     = tile_e[tile];
    const int sbase = tile_s[tile];
    const int rows  = tile_rows[tile];
    const int nbase = blockIdx.y * TM;    // over HID

    __shared__ __align__(16) u16 As[2][TM * BK];
    __shared__ __align__(16) u16 Bs[2][TM * BK];

    const int th = threadIdx.x;
    const int w  = th >> 6;
    const int l  = th & 63;
    const int wm = w >> 1, wn = w & 1;
    const int lr = l >> 3;          // 0..7: row within 8-row staging group
    const int lc = (l & 7) * 8;     // u16 offset within row (16B chunks)

    // staging source pointers (per thread, fixed rows across K)
    const u16* aptr[4];
    const u16* bptr[4];
    const u16* wb = w1t + (size_t)e * HID * DIM + (size_t)nbase * DIM;
    #pragma unroll
    for (int c = 0; c < 4; c++) {
        const int r = w * 32 + c * 8 + lr;
        int srow = sbase + r; if (srow > T_TOK - 1) srow = T_TOK - 1;
        aptr[c] = xs + (size_t)srow * DIM + lc;
        bptr[c] = wb + (size_t)r * DIM + lc;
    }

    f32x16 acc[2][2] = {};

    auto stage = [&](int buf, int k0) {
        #pragma unroll
        for (int c = 0; c < 4; c++) {
            const int r = w * 32 + c * 8;
            gld_lds16(aptr[c] + k0, &As[buf][r * BK]);
            gld_lds16(bptr[c] + k0, &Bs[buf][r * BK]);
        }
    };

    int cur = 0;
    stage(0, 0);
    const int NIT = DIM / BK;   // 16
    for (int it = 0; it < NIT; ++it) {
        __syncthreads();   // drains this wave's loads into buf[cur]; syncs block
        if (it + 1 < NIT) stage(cur ^ 1, (it + 1) * BK);
        #pragma unroll
        for (int ks = 0; ks < 4; ks++) {
            const int ko = ks * 16 + (l >> 5) * 8;
            bf16x8 af[2], bf[2];
            #pragma unroll
            for (int i = 0; i < 2; i++) {
                af[i] = *(const bf16x8*)&As[cur][(wm * 64 + i * 32 + (l & 31)) * BK + ko];
                bf[i] = *(const bf16x8*)&Bs[cur][(wn * 64 + i * 32 + (l & 31)) * BK + ko];
            }
            #pragma unroll
            for (int mi = 0; mi < 2; mi++)
                #pragma unroll
                for (int ni = 0; ni < 2; ni++)
                    acc[mi][ni] = __builtin_amdgcn_mfma_f32_32x32x16_bf16(
                        af[mi], bf[ni], acc[mi][ni], 0, 0, 0);
        }
        cur ^= 1;
    }

    // C/D layout (32x32): col = lane&31, row = (reg&3) + 8*(reg>>2) + 4*(lane>>5)
    const int col = l & 31;
    const int rbase = (l >> 5) * 4;
    #pragma unroll
    for (int ni = 0; ni < 2; ni++) {
        const int n = nbase + wn * 64 + ni * 32 + col;
        const float bias = b1[e * HID + n];
        #pragma unroll
        for (int mi = 0; mi < 2; mi++) {
            #pragma unroll
            for (int r = 0; r < 16; r++) {
                const int m = wm * 64 + mi * 32 + (r & 3) + 8 * (r >> 2) + rbase;
                if (m < rows) {
                    float v = acc[mi][ni][r] + bias;
                    h_buf[(size_t)(sbase + m) * HID + n] = f2bf(gelu_exact(v));
                }
            }
        }
    }
}

// ---------------------------------------------------------------------------
// FFN2 (MFMA 32x32x16, double-buffered):
// y = x + (h @ W2t^T + b2) * top_val, scattered to token order (fp32 out).
// h: [4096][HID] bf16 sorted. W2t: [E][DIM][HID] bf16.
// ---------------------------------------------------------------------------
__global__ __launch_bounds__(256) void ffn2_mfma(
    const u16* __restrict__ h_buf, const u16* __restrict__ w2t,
    const float* __restrict__ b2, const float* __restrict__ x,
    const int* __restrict__ sorted_tok, const float* __restrict__ top_val,
    const int* __restrict__ tile_e, const int* __restrict__ tile_s,
    const int* __restrict__ tile_rows, const int* __restrict__ ntiles,
    float* __restrict__ yout)
{
    const int tile = blockIdx.x;
    if (tile >= *ntiles) return;
    const int e     = tile_e[tile];
    const int sbase = tile_s[tile];
    const int rows  = tile_rows[tile];
    const int nbase = blockIdx.y * TM;    // over DIM

    __shared__ __align__(16) u16 As[2][TM * BK];
    __shared__ __align__(16) u16 Bs[2][TM * BK];

    const int th = threadIdx.x;
    const int w  = th >> 6;
    const int l  = th & 63;
    const int wm = w >> 1, wn = w & 1;
    const int lr = l >> 3;
    const int lc = (l & 7) * 8;

    const u16* aptr[4];
    const u16* bptr[4];
    const u16* wb = w2t + (size_t)e * DIM * HID + (size_t)nbase * HID;
    #pragma unroll
    for (int c = 0; c < 4; c++) {
        const int r = w * 32 + c * 8 + lr;
        int srow = sbase + r; if (srow > T_TOK - 1) srow = T_TOK - 1;
        aptr[c] = h_buf + (size_t)srow * HID + lc;
        bptr[c] = wb + (size_t)r * HID + lc;
    }

    f32x16 acc[2][2] = {};

    auto stage = [&](int buf, int k0) {
        #pragma unroll
        for (int c = 0; c < 4; c++) {
            const int r = w * 32 + c * 8;
            gld_lds16(aptr[c] + k0, &As[buf][r * BK]);
            gld_lds16(bptr[c] + k0, &Bs[buf][r * BK]);
        }
    };

    int cur = 0;
    stage(0, 0);
    const int NIT = HID / BK;   // 32
    for (int it = 0; it < NIT; ++it) {
        __syncthreads();
        if (it + 1 < NIT) stage(cur ^ 1, (it + 1) * BK);
        #pragma unroll
        for (int ks = 0; ks < 4; ks++) {
            const int ko = ks * 16 + (l >> 5) * 8;
            bf16x8 af[2], bf[2];
            #pragma unroll
            for (int i = 0; i < 2; i++) {
                af[i] = *(const bf16x8*)&As[cur][(wm * 64 + i * 32 + (l & 31)) * BK + ko];
                bf[i] = *(const bf16x8*)&Bs[cur][(wn * 64 + i * 32 + (l & 31)) * BK + ko];
            }
            #pragma unroll
            for (int mi = 0; mi < 2; mi++)
                #pragma unroll
                for (int ni = 0; ni < 2; ni++)
                    acc[mi][ni] = __builtin_amdgcn_mfma_f32_32x32x16_bf16(
                        af[mi], bf[ni], acc[mi][ni], 0, 0, 0);
        }
        cur ^= 1;
    }

    const int col = l & 31;
    const int rbase = (l >> 5) * 4;
    float bias[2];
    #pragma unroll
    for (int ni = 0; ni < 2; ni++)
        bias[ni] = b2[e * DIM + nbase + wn * 64 + ni * 32 + col];

    #pragma unroll
    for (int mi = 0; mi < 2; mi++) {
        #pragma unroll
        for (int r = 0; r < 16; r++) {
            const int m = wm * 64 + mi * 32 + (r & 3) + 8 * (r >> 2) + rbase;
            if (m < rows) {
                const int t = sorted_tok[sbase + m];
                const float tv = top_val[t];
                #pragma unroll
                for (int ni = 0; ni < 2; ni++) {
                    const int n = nbase + wn * 64 + ni * 32 + col;
                    float v = acc[mi][ni][r] + bias[ni];
                    yout[(size_t)t * DIM + n] = x[(size_t)t * DIM + n] + v * tv;
                }
            }
        }
    }
}

// ---------------------------------------------------------------------------
// RMSNorm (F.normalize * gamma * sqrt(D)) + exact GeLU, in place.
// ---------------------------------------------------------------------------
__global__ __launch_bounds__(256) void norm_kernel(float* __restrict__ y,
                                                   const float* __restrict__ gamma)
{
    const int t = blockIdx.x;
    float* row = y + (size_t)t * DIM;
    const int th = threadIdx.x;
    float4 v = *(const float4*)&row[th * 4];
    float ss = v.x * v.x + v.y * v.y + v.z * v.z + v.w * v.w;

    const int lane = th & 63, wave = th >> 6;
    #pragma unroll
    for (int off = 32; off > 0; off >>= 1) ss += __shfl_down(ss, off, 64);
    __shared__ float red[4];
    if (lane == 0) red[wave] = ss;
    __syncthreads();
    float total = red[0] + red[1] + red[2] + red[3];

    float nrm = sqrtf(total);
    float scale = 32.0f / fmaxf(nrm, 1e-12f);   // sqrt(1024) = 32

    float4 g = *(const float4*)&gamma[th * 4];
    float4 o;
    o.x = gelu_exact(v.x * scale * g.x);
    o.y = gelu_exact(v.y * scale * g.y);
    o.z = gelu_exact(v.z * scale * g.z);
    o.w = gelu_exact(v.w * scale * g.w);
    *(float4*)&row[th * 4] = o;
}

// ---------------------------------------------------------------------------
extern "C" void kernel_launch(void* const* d_in, const int* in_sizes, int n_in,
                              void* d_out, int out_size, void* d_ws, size_t ws_size,
                              hipStream_t stream) {
    const float* x      = (const float*)d_in[0];
    const float* gate_w = (const float*)d_in[1];
    const float* gate_b = (const float*)d_in[2];
    const float* w1     = (const float*)d_in[3];
    const float* b1     = (const float*)d_in[4];
    const float* w2     = (const float*)d_in[5];
    const float* b2     = (const float*)d_in[6];
    const float* gamma  = (const float*)d_in[7];

    float* out  = (float*)d_out;                  // [T*D] y, then [1] loss
    float* loss = out + (size_t)T_TOK * DIM;

    char* ws = (char*)d_ws;
    float* top_val    = (float*)(ws + 0);         // 4096 f
    int*   top_idx    = (int*)  (ws + 16384);     // 4096 i
    int*   sorted_tok = (int*)  (ws + 32768);     // 4096 i
    float* importance = (float*)(ws + 49152);     // 8 f  (zeroed)
    int*   counts     = (int*)  (ws + 49184);     // 8 i  (zeroed)
    int*   cursors    = (int*)  (ws + 49216);     // 8 i  (zeroed)
    int*   offsets    = (int*)  (ws + 49248);     // 9 i
    int*   tile_e     = (int*)  (ws + 49536);     // 40 i
    int*   tile_s     = (int*)  (ws + 49824);     // 40 i
    int*   tile_rows  = (int*)  (ws + 50112);     // 40 i
    int*   ntiles     = (int*)  (ws + 50400);     // 1 i
    u16*   x_sorted   = (u16*)  (ws + 65536);                    // 8 MiB
    u16*   h_buf      = (u16*)  (ws + 65536 + 8388608);          // 16 MiB
    u16*   w1t        = (u16*)  (ws + 65536 + 8388608 + 16777216);            // 32 MiB
    u16*   w2t        = (u16*)  (ws + 65536 + 8388608 + 16777216 + 33554432); // 32 MiB

    hipMemsetAsync(ws + 49152, 0, 96, stream);

    gate_kernel<<<T_TOK / 4, 256, 0, stream>>>(x, gate_w, gate_b, top_val,
                                               top_idx, importance, counts);
    plan_kernel<<<1, 64, 0, stream>>>(counts, importance, offsets, tile_e,
                                      tile_s, tile_rows, ntiles, loss);
    scatter_kernel<<<T_TOK / 256, 256, 0, stream>>>(top_idx, offsets, cursors,
                                                    sorted_tok);
    gather_x_kernel<<<T_TOK, 256, 0, stream>>>(x, sorted_tok, x_sorted);
    // w1 [E][D][H] -> w1t [E][H][D]
    transpose_bf16_kernel<<<dim3(HID / 32, DIM / 32, NE), 256, 0, stream>>>(
        w1, w1t, DIM, HID);
    // w2 [E][H][D] -> w2t [E][D][H]
    transpose_bf16_kernel<<<dim3(DIM / 32, HID / 32, NE), 256, 0, stream>>>(
        w2, w2t, HID, DIM);

    ffn1_mfma<<<dim3(40, HID / TM), 256, 0, stream>>>(
        x_sorted, w1t, b1, tile_e, tile_s, tile_rows, ntiles, h_buf);
    ffn2_mfma<<<dim3(40, DIM / TM), 256, 0, stream>>>(
        h_buf, w2t, b2, x, sorted_tok, top_val, tile_e, tile_s, tile_rows,
        ntiles, out);
    norm_kernel<<<T_TOK, 256, 0, stream>>>(out, gamma);
}

// Round 4
// 346.780 us; speedup vs baseline: 1.3056x; 1.3056x over previous
//
#include <hip/hip_runtime.h>
#include <math.h>

// Problem constants (B=4, N=1024, D=1024, H=2048, E=8)
#define T_TOK 4096
#define DIM   1024
#define HID   2048
#define NE    8
#define TMM   128   // M tile (tokens)
#define TNN   64    // N tile
#define BK    64    // K chunk (bf16)

typedef unsigned int  u32;
typedef unsigned short u16;
typedef __attribute__((ext_vector_type(8))) short bf16x8;  // 8 bf16 in 4 VGPRs
typedef __attribute__((ext_vector_type(4))) float f32x4;

__device__ __forceinline__ float gelu_exact(float v) {
    return 0.5f * v * (1.0f + erff(v * 0.70710678118654752440f));
}

// tanh-form gelu: max abs err vs exact ~1e-3; one v_exp instead of erff poly
__device__ __forceinline__ float gelu_fast(float x) {
    float u = 1.5957691216057308f * (x + 0.044715f * x * x * x); // 2*0.79788456
    float e = __expf(u);                  // exp(2u')
    float t = 1.f - 2.f / (e + 1.f);      // tanh(u')
    return 0.5f * x * (1.f + t);
}

__device__ __forceinline__ u16 f2bf(float v) {
    u32 u = __float_as_uint(v);
    u32 r = (u + 0x7FFFu + ((u >> 16) & 1u)) >> 16;   // RNE
    return (u16)r;
}

// async global->LDS, 16B per lane; lds dest = wave-uniform base + lane*16
__device__ __forceinline__ void gld_lds16(const void* g, void* l) {
    __builtin_amdgcn_global_load_lds(
        (const __attribute__((address_space(1))) u32*)g,
        (__attribute__((address_space(3))) u32*)l,
        16, 0, 0);
}

// ---------------------------------------------------------------------------
// Gate: logits = x @ gate_w + gate_b ; softmax ; top-1 ; importance sums
// ---------------------------------------------------------------------------
__global__ __launch_bounds__(256) void gate_kernel(
    const float* __restrict__ x, const float* __restrict__ gw,
    const float* __restrict__ gb, float* __restrict__ top_val,
    int* __restrict__ top_idx, float* __restrict__ importance,
    int* __restrict__ counts)
{
    __shared__ float s_imp[NE];
    __shared__ int   s_cnt[NE];
    if (threadIdx.x < NE) { s_imp[threadIdx.x] = 0.f; s_cnt[threadIdx.x] = 0; }
    __syncthreads();

    const int wave = threadIdx.x >> 6;
    const int lane = threadIdx.x & 63;
    const int t = blockIdx.x * 4 + wave;

    float acc[NE];
    #pragma unroll
    for (int e = 0; e < NE; e++) acc[e] = 0.f;

    const float* xr = x + (size_t)t * DIM;
    #pragma unroll 4
    for (int k = lane; k < DIM; k += 64) {
        float xv = xr[k];
        const float* g = gw + (size_t)k * NE;
        float4 g0 = *(const float4*)g;
        float4 g1 = *(const float4*)(g + 4);
        acc[0] += xv * g0.x; acc[1] += xv * g0.y;
        acc[2] += xv * g0.z; acc[3] += xv * g0.w;
        acc[4] += xv * g1.x; acc[5] += xv * g1.y;
        acc[6] += xv * g1.z; acc[7] += xv * g1.w;
    }
    #pragma unroll
    for (int e = 0; e < NE; e++) {
        #pragma unroll
        for (int off = 32; off > 0; off >>= 1)
            acc[e] += __shfl_down(acc[e], off, 64);
    }
    if (lane == 0) {
        float l[NE];
        float m = -1e30f;
        #pragma unroll
        for (int e = 0; e < NE; e++) { l[e] = acc[e] + gb[e]; m = fmaxf(m, l[e]); }
        float s = 0.f;
        #pragma unroll
        for (int e = 0; e < NE; e++) { l[e] = expf(l[e] - m); s += l[e]; }
        float inv = 1.f / s;
        int bi = 0; float bv = -1.f;
        #pragma unroll
        for (int e = 0; e < NE; e++) {
            float p = l[e] * inv;
            atomicAdd(&s_imp[e], p);
            if (p > bv) { bv = p; bi = e; }
        }
        top_val[t] = bv;
        top_idx[t] = bi;
        atomicAdd(&s_cnt[bi], 1);
    }
    __syncthreads();
    if (threadIdx.x < NE) {
        atomicAdd(&importance[threadIdx.x], s_imp[threadIdx.x]);
        atomicAdd(&counts[threadIdx.x],     s_cnt[threadIdx.x]);
    }
}

// ---------------------------------------------------------------------------
// Plan: expert offsets, 128-row tile table, load-balance loss.
// ---------------------------------------------------------------------------
__global__ void plan_kernel(const int* __restrict__ counts,
                            const float* __restrict__ importance,
                            int* __restrict__ offsets, int* __restrict__ tile_e,
                            int* __restrict__ tile_s, int* __restrict__ tile_rows,
                            int* __restrict__ ntiles, float* __restrict__ loss_out)
{
    if (threadIdx.x == 0 && blockIdx.x == 0) {
        int off = 0, nt = 0;
        for (int e = 0; e < NE; e++) {
            offsets[e] = off;
            int c = counts[e];
            for (int s = 0; s < c; s += TMM) {
                tile_e[nt] = e;
                tile_s[nt] = off + s;
                tile_rows[nt] = min(TMM, c - s);
                nt++;
            }
            off += c;
        }
        offsets[NE] = off;
        *ntiles = nt;   // <= 4096/128 + 8 = 40

        float mean = 0.f;
        for (int e = 0; e < NE; e++) mean += importance[e];
        mean *= (1.0f / NE);
        float var = 0.f;
        for (int e = 0; e < NE; e++) { float d = importance[e] - mean; var += d * d; }
        var *= (1.0f / (NE - 1));
        loss_out[0] = var / (mean * mean + 1e-10f);
    }
}

// ---------------------------------------------------------------------------
// Scatter: sorted token list per expert.
// ---------------------------------------------------------------------------
__global__ void scatter_kernel(const int* __restrict__ top_idx,
                               const int* __restrict__ offsets,
                               int* __restrict__ cursors,
                               int* __restrict__ sorted_tok)
{
    int t = blockIdx.x * blockDim.x + threadIdx.x;
    if (t < T_TOK) {
        int e = top_idx[t];
        int pos = atomicAdd(&cursors[e], 1);
        sorted_tok[offsets[e] + pos] = t;
    }
}

// ---------------------------------------------------------------------------
// Gather x rows into sorted order, fp32 -> bf16. One block per sorted row.
// ---------------------------------------------------------------------------
__global__ __launch_bounds__(256) void gather_x_kernel(
    const float* __restrict__ x, const int* __restrict__ sorted_tok,
    u16* __restrict__ xs)
{
    const int s = blockIdx.x;
    const int tok = sorted_tok[s];
    const float* src = x + (size_t)tok * DIM;
    u16* dst = xs + (size_t)s * DIM;
    const int i = threadIdx.x * 4;
    float4 v = *(const float4*)&src[i];
    ushort4 o;
    o.x = f2bf(v.x); o.y = f2bf(v.y); o.z = f2bf(v.z); o.w = f2bf(v.w);
    *(ushort4*)&dst[i] = o;
}

// ---------------------------------------------------------------------------
// Transpose + convert: in [E][R][C] f32  ->  out [E][C][R] bf16
// grid (C/32, R/32, E), block 256.
// ---------------------------------------------------------------------------
__global__ __launch_bounds__(256) void transpose_bf16_kernel(
    const float* __restrict__ in, u16* __restrict__ out, int R, int C)
{
    __shared__ float tile[32][33];
    const float* src = in  + (size_t)blockIdx.z * R * C;
    u16*         dst = out + (size_t)blockIdx.z * R * C;
    const int c0 = blockIdx.x * 32, r0 = blockIdx.y * 32;
    const int tc = threadIdx.x & 31, tr = threadIdx.x >> 5;  // tr in 0..7
    #pragma unroll
    for (int i = 0; i < 4; i++) {
        int r = tr + i * 8;
        tile[r][tc] = src[(size_t)(r0 + r) * C + c0 + tc];
    }
    __syncthreads();
    #pragma unroll
    for (int i = 0; i < 4; i++) {
        int cc = tr + i * 8;      // output row = c0+cc
        float v = tile[tc][cc];   // stride-33 read: conflict-free
        dst[(size_t)(c0 + cc) * R + r0 + tc] = f2bf(v);
    }
}

// ---------------------------------------------------------------------------
// FFN1 (MFMA 16x16x32, single-buffer, 128x64 tile):
// h = gelu(Xs @ W1t^T + b1) in sorted order, bf16 out.
// Xs: [4096][DIM] bf16 (sorted). W1t: [E][HID][DIM] bf16. h: [4096][HID] bf16.
// 4 waves in 2x2; wave tile 64Mx32N = 4x2 accs of 16x16.
// ---------------------------------------------------------------------------
__global__ __launch_bounds__(256) void ffn1_mfma(
    const u16* __restrict__ xs, const u16* __restrict__ w1t,
    const float* __restrict__ b1,
    const int* __restrict__ tile_e, const int* __restrict__ tile_s,
    const int* __restrict__ tile_rows, const int* __restrict__ ntiles,
    u16* __restrict__ h_buf)
{
    const int tile = blockIdx.x;
    if (tile >= *ntiles) return;
    const int e     = tile_e[tile];
    const int sbase = tile_s[tile];
    const int rows  = tile_rows[tile];
    const int nbase = blockIdx.y * TNN;    // over HID

    __shared__ __align__(16) u16 As[TMM * BK];   // 16 KB
    __shared__ __align__(16) u16 Bs[TNN * BK];   // 8 KB

    const int th = threadIdx.x;
    const int w  = th >> 6;
    const int l  = th & 63;
    const int wm = w >> 1, wn = w & 1;
    const int lr = l >> 3;          // 0..7 row in staging group
    const int lc = (l & 7) * 8;     // u16 col offset (16B chunks)

    // A staging: 4 groups of 8 rows per wave (128 rows total)
    const u16* aptr[4];
    #pragma unroll
    for (int c = 0; c < 4; c++) {
        int srow = sbase + w * 32 + c * 8 + lr;
        if (srow > T_TOK - 1) srow = T_TOK - 1;
        aptr[c] = xs + (size_t)srow * DIM + lc;
    }
    // B staging: 2 groups of 8 rows per wave (64 rows total)
    const u16* wb = w1t + (size_t)e * HID * DIM + (size_t)nbase * DIM;
    const u16* bptr[2];
    #pragma unroll
    for (int c = 0; c < 2; c++)
        bptr[c] = wb + (size_t)(w * 16 + c * 8 + lr) * DIM + lc;

    f32x4 acc[4][2] = {};

    for (int k0 = 0; k0 < DIM; k0 += BK) {
        __syncthreads();
        #pragma unroll
        for (int c = 0; c < 4; c++)
            gld_lds16(aptr[c] + k0, &As[(w * 32 + c * 8) * BK]);
        #pragma unroll
        for (int c = 0; c < 2; c++)
            gld_lds16(bptr[c] + k0, &Bs[(w * 16 + c * 8) * BK]);
        __syncthreads();
        #pragma unroll
        for (int ks = 0; ks < 2; ks++) {
            const int ko = ks * 32 + (l >> 4) * 8;
            bf16x8 af[4], bfr[2];
            #pragma unroll
            for (int i = 0; i < 4; i++)
                af[i]  = *(const bf16x8*)&As[(wm * 64 + i * 16 + (l & 15)) * BK + ko];
            #pragma unroll
            for (int i = 0; i < 2; i++)
                bfr[i] = *(const bf16x8*)&Bs[(wn * 32 + i * 16 + (l & 15)) * BK + ko];
            #pragma unroll
            for (int mi = 0; mi < 4; mi++)
                #pragma unroll
                for (int ni = 0; ni < 2; ni++)
                    acc[mi][ni] = __builtin_amdgcn_mfma_f32_16x16x32_bf16(
                        af[mi], bfr[ni], acc[mi][ni], 0, 0, 0);
        }
    }

    const int col = l & 15, quad = l >> 4;
    #pragma unroll
    for (int ni = 0; ni < 2; ni++) {
        const int n = nbase + wn * 32 + ni * 16 + col;
        const float bias = b1[e * HID + n];
        #pragma unroll
        for (int mi = 0; mi < 4; mi++) {
            #pragma unroll
            for (int r = 0; r < 4; r++) {
                const int m = wm * 64 + mi * 16 + quad * 4 + r;
                if (m < rows) {
                    float v = acc[mi][ni][r] + bias;
                    h_buf[(size_t)(sbase + m) * HID + n] = f2bf(gelu_fast(v));
                }
            }
        }
    }
}

// ---------------------------------------------------------------------------
// FFN2 (MFMA 16x16x32, single-buffer, 128x64 tile):
// y = x + (h @ W2t^T + b2) * top_val, scattered to token order (fp32 out).
// ---------------------------------------------------------------------------
__global__ __launch_bounds__(256) void ffn2_mfma(
    const u16* __restrict__ h_buf, const u16* __restrict__ w2t,
    const float* __restrict__ b2, const float* __restrict__ x,
    const int* __restrict__ sorted_tok, const float* __restrict__ top_val,
    const int* __restrict__ tile_e, const int* __restrict__ tile_s,
    const int* __restrict__ tile_rows, const int* __restrict__ ntiles,
    float* __restrict__ yout)
{
    const int tile = blockIdx.x;
    if (tile >= *ntiles) return;
    const int e     = tile_e[tile];
    const int sbase = tile_s[tile];
    const int rows  = tile_rows[tile];
    const int nbase = blockIdx.y * TNN;    // over DIM

    __shared__ __align__(16) u16 As[TMM * BK];
    __shared__ __align__(16) u16 Bs[TNN * BK];

    const int th = threadIdx.x;
    const int w  = th >> 6;
    const int l  = th & 63;
    const int wm = w >> 1, wn = w & 1;
    const int lr = l >> 3;
    const int lc = (l & 7) * 8;

    const u16* aptr[4];
    #pragma unroll
    for (int c = 0; c < 4; c++) {
        int srow = sbase + w * 32 + c * 8 + lr;
        if (srow > T_TOK - 1) srow = T_TOK - 1;
        aptr[c] = h_buf + (size_t)srow * HID + lc;
    }
    const u16* wb = w2t + (size_t)e * DIM * HID + (size_t)nbase * HID;
    const u16* bptr[2];
    #pragma unroll
    for (int c = 0; c < 2; c++)
        bptr[c] = wb + (size_t)(w * 16 + c * 8 + lr) * HID + lc;

    f32x4 acc[4][2] = {};

    for (int k0 = 0; k0 < HID; k0 += BK) {
        __syncthreads();
        #pragma unroll
        for (int c = 0; c < 4; c++)
            gld_lds16(aptr[c] + k0, &As[(w * 32 + c * 8) * BK]);
        #pragma unroll
        for (int c = 0; c < 2; c++)
            gld_lds16(bptr[c] + k0, &Bs[(w * 16 + c * 8) * BK]);
        __syncthreads();
        #pragma unroll
        for (int ks = 0; ks < 2; ks++) {
            const int ko = ks * 32 + (l >> 4) * 8;
            bf16x8 af[4], bfr[2];
            #pragma unroll
            for (int i = 0; i < 4; i++)
                af[i]  = *(const bf16x8*)&As[(wm * 64 + i * 16 + (l & 15)) * BK + ko];
            #pragma unroll
            for (int i = 0; i < 2; i++)
                bfr[i] = *(const bf16x8*)&Bs[(wn * 32 + i * 16 + (l & 15)) * BK + ko];
            #pragma unroll
            for (int mi = 0; mi < 4; mi++)
                #pragma unroll
                for (int ni = 0; ni < 2; ni++)
                    acc[mi][ni] = __builtin_amdgcn_mfma_f32_16x16x32_bf16(
                        af[mi], bfr[ni], acc[mi][ni], 0, 0, 0);
        }
    }

    const int col = l & 15, quad = l >> 4;
    float bias[2];
    #pragma unroll
    for (int ni = 0; ni < 2; ni++)
        bias[ni] = b2[e * DIM + nbase + wn * 32 + ni * 16 + col];

    #pragma unroll
    for (int mi = 0; mi < 4; mi++) {
        #pragma unroll
        for (int r = 0; r < 4; r++) {
            const int m = wm * 64 + mi * 16 + quad * 4 + r;
            if (m < rows) {
                const int t = sorted_tok[sbase + m];
                const float tv = top_val[t];
                #pragma unroll
                for (int ni = 0; ni < 2; ni++) {
                    const int n = nbase + wn * 32 + ni * 16 + col;
                    float v = acc[mi][ni][r] + bias[ni];
                    yout[(size_t)t * DIM + n] = x[(size_t)t * DIM + n] + v * tv;
                }
            }
        }
    }
}

// ---------------------------------------------------------------------------
// RMSNorm (F.normalize * gamma * sqrt(D)) + exact GeLU, in place.
// ---------------------------------------------------------------------------
__global__ __launch_bounds__(256) void norm_kernel(float* __restrict__ y,
                                                   const float* __restrict__ gamma)
{
    const int t = blockIdx.x;
    float* row = y + (size_t)t * DIM;
    const int th = threadIdx.x;
    float4 v = *(const float4*)&row[th * 4];
    float ss = v.x * v.x + v.y * v.y + v.z * v.z + v.w * v.w;

    const int lane = th & 63, wave = th >> 6;
    #pragma unroll
    for (int off = 32; off > 0; off >>= 1) ss += __shfl_down(ss, off, 64);
    __shared__ float red[4];
    if (lane == 0) red[wave] = ss;
    __syncthreads();
    float total = red[0] + red[1] + red[2] + red[3];

    float nrm = sqrtf(total);
    float scale = 32.0f / fmaxf(nrm, 1e-12f);   // sqrt(1024) = 32

    float4 g = *(const float4*)&gamma[th * 4];
    float4 o;
    o.x = gelu_exact(v.x * scale * g.x);
    o.y = gelu_exact(v.y * scale * g.y);
    o.z = gelu_exact(v.z * scale * g.z);
    o.w = gelu_exact(v.w * scale * g.w);
    *(float4*)&row[th * 4] = o;
}

// ---------------------------------------------------------------------------
extern "C" void kernel_launch(void* const* d_in, const int* in_sizes, int n_in,
                              void* d_out, int out_size, void* d_ws, size_t ws_size,
                              hipStream_t stream) {
    const float* x      = (const float*)d_in[0];
    const float* gate_w = (const float*)d_in[1];
    const float* gate_b = (const float*)d_in[2];
    const float* w1     = (const float*)d_in[3];
    const float* b1     = (const float*)d_in[4];
    const float* w2     = (const float*)d_in[5];
    const float* b2     = (const float*)d_in[6];
    const float* gamma  = (const float*)d_in[7];

    float* out  = (float*)d_out;                  // [T*D] y, then [1] loss
    float* loss = out + (size_t)T_TOK * DIM;

    char* ws = (char*)d_ws;
    float* top_val    = (float*)(ws + 0);         // 4096 f
    int*   top_idx    = (int*)  (ws + 16384);     // 4096 i
    int*   sorted_tok = (int*)  (ws + 32768);     // 4096 i
    float* importance = (float*)(ws + 49152);     // 8 f  (zeroed)
    int*   counts     = (int*)  (ws + 49184);     // 8 i  (zeroed)
    int*   cursors    = (int*)  (ws + 49216);     // 8 i  (zeroed)
    int*   offsets    = (int*)  (ws + 49248);     // 9 i
    int*   tile_e     = (int*)  (ws + 49536);     // 40 i
    int*   tile_s     = (int*)  (ws + 49824);     // 40 i
    int*   tile_rows  = (int*)  (ws + 50112);     // 40 i
    int*   ntiles     = (int*)  (ws + 50400);     // 1 i
    u16*   x_sorted   = (u16*)  (ws + 65536);                    // 8 MiB
    u16*   h_buf      = (u16*)  (ws + 65536 + 8388608);          // 16 MiB
    u16*   w1t        = (u16*)  (ws + 65536 + 8388608 + 16777216);            // 32 MiB
    u16*   w2t        = (u16*)  (ws + 65536 + 8388608 + 16777216 + 33554432); // 32 MiB

    hipMemsetAsync(ws + 49152, 0, 96, stream);

    gate_kernel<<<T_TOK / 4, 256, 0, stream>>>(x, gate_w, gate_b, top_val,
                                               top_idx, importance, counts);
    plan_kernel<<<1, 64, 0, stream>>>(counts, importance, offsets, tile_e,
                                      tile_s, tile_rows, ntiles, loss);
    scatter_kernel<<<T_TOK / 256, 256, 0, stream>>>(top_idx, offsets, cursors,
                                                    sorted_tok);
    gather_x_kernel<<<T_TOK, 256, 0, stream>>>(x, sorted_tok, x_sorted);
    // w1 [E][D][H] -> w1t [E][H][D]
    transpose_bf16_kernel<<<dim3(HID / 32, DIM / 32, NE), 256, 0, stream>>>(
        w1, w1t, DIM, HID);
    // w2 [E][H][D] -> w2t [E][D][H]
    transpose_bf16_kernel<<<dim3(DIM / 32, HID / 32, NE), 256, 0, stream>>>(
        w2, w2t, HID, DIM);

    ffn1_mfma<<<dim3(40, HID / TNN), 256, 0, stream>>>(
        x_sorted, w1t, b1, tile_e, tile_s, tile_rows, ntiles, h_buf);
    ffn2_mfma<<<dim3(40, DIM / TNN), 256, 0, stream>>>(
        h_buf, w2t, b2, x, sorted_tok, top_val, tile_e, tile_s, tile_rows,
        ntiles, out);
    norm_kernel<<<T_TOK, 256, 0, stream>>>(out, gamma);
}

// Round 5
// 334.612 us; speedup vs baseline: 1.3531x; 1.0364x over previous
//
#include <hip/hip_runtime.h>
#include <math.h>

// Problem constants (B=4, N=1024, D=1024, H=2048, E=8)
#define T_TOK 4096
#define DIM   1024
#define HID   2048
#define NE    8
#define TMM   128   // M tile (tokens)
#define TNN   64    // N tile
#define BK    64    // K chunk (bf16)

typedef unsigned int  u32;
typedef unsigned short u16;
typedef __attribute__((ext_vector_type(8))) short bf16x8;  // 8 bf16 in 4 VGPRs
typedef __attribute__((ext_vector_type(4))) float f32x4;

__device__ __forceinline__ float gelu_exact(float v) {
    return 0.5f * v * (1.0f + erff(v * 0.70710678118654752440f));
}

// tanh-form gelu: max abs err vs exact ~1e-3; one v_exp instead of erff poly
__device__ __forceinline__ float gelu_fast(float x) {
    float u = 1.5957691216057308f * (x + 0.044715f * x * x * x); // 2*0.79788456
    float e = __expf(u);                  // exp(2u')
    float t = 1.f - 2.f / (e + 1.f);      // tanh(u')
    return 0.5f * x * (1.f + t);
}

__device__ __forceinline__ u16 f2bf(float v) {
    u32 u = __float_as_uint(v);
    u32 r = (u + 0x7FFFu + ((u >> 16) & 1u)) >> 16;   // RNE
    return (u16)r;
}

// async global->LDS, 16B per lane; lds dest = wave-uniform base + lane*16
__device__ __forceinline__ void gld_lds16(const void* g, void* l) {
    __builtin_amdgcn_global_load_lds(
        (const __attribute__((address_space(1))) u32*)g,
        (__attribute__((address_space(3))) u32*)l,
        16, 0, 0);
}

// ---------------------------------------------------------------------------
// Gate: logits = x @ gate_w + gate_b ; softmax ; top-1 ; importance sums
// ---------------------------------------------------------------------------
__global__ __launch_bounds__(256) void gate_kernel(
    const float* __restrict__ x, const float* __restrict__ gw,
    const float* __restrict__ gb, float* __restrict__ top_val,
    int* __restrict__ top_idx, float* __restrict__ importance,
    int* __restrict__ counts)
{
    __shared__ float s_imp[NE];
    __shared__ int   s_cnt[NE];
    if (threadIdx.x < NE) { s_imp[threadIdx.x] = 0.f; s_cnt[threadIdx.x] = 0; }
    __syncthreads();

    const int wave = threadIdx.x >> 6;
    const int lane = threadIdx.x & 63;
    const int t = blockIdx.x * 4 + wave;

    float acc[NE];
    #pragma unroll
    for (int e = 0; e < NE; e++) acc[e] = 0.f;

    const float* xr = x + (size_t)t * DIM;
    #pragma unroll 4
    for (int k = lane; k < DIM; k += 64) {
        float xv = xr[k];
        const float* g = gw + (size_t)k * NE;
        float4 g0 = *(const float4*)g;
        float4 g1 = *(const float4*)(g + 4);
        acc[0] += xv * g0.x; acc[1] += xv * g0.y;
        acc[2] += xv * g0.z; acc[3] += xv * g0.w;
        acc[4] += xv * g1.x; acc[5] += xv * g1.y;
        acc[6] += xv * g1.z; acc[7] += xv * g1.w;
    }
    #pragma unroll
    for (int e = 0; e < NE; e++) {
        #pragma unroll
        for (int off = 32; off > 0; off >>= 1)
            acc[e] += __shfl_down(acc[e], off, 64);
    }
    if (lane == 0) {
        float l[NE];
        float m = -1e30f;
        #pragma unroll
        for (int e = 0; e < NE; e++) { l[e] = acc[e] + gb[e]; m = fmaxf(m, l[e]); }
        float s = 0.f;
        #pragma unroll
        for (int e = 0; e < NE; e++) { l[e] = expf(l[e] - m); s += l[e]; }
        float inv = 1.f / s;
        int bi = 0; float bv = -1.f;
        #pragma unroll
        for (int e = 0; e < NE; e++) {
            float p = l[e] * inv;
            atomicAdd(&s_imp[e], p);
            if (p > bv) { bv = p; bi = e; }
        }
        top_val[t] = bv;
        top_idx[t] = bi;
        atomicAdd(&s_cnt[bi], 1);
    }
    __syncthreads();
    if (threadIdx.x < NE) {
        atomicAdd(&importance[threadIdx.x], s_imp[threadIdx.x]);
        atomicAdd(&counts[threadIdx.x],     s_cnt[threadIdx.x]);
    }
}

// ---------------------------------------------------------------------------
// Plan: expert offsets, 128-row tile table, load-balance loss.
// ---------------------------------------------------------------------------
__global__ void plan_kernel(const int* __restrict__ counts,
                            const float* __restrict__ importance,
                            int* __restrict__ offsets, int* __restrict__ tile_e,
                            int* __restrict__ tile_s, int* __restrict__ tile_rows,
                            int* __restrict__ ntiles, float* __restrict__ loss_out)
{
    if (threadIdx.x == 0 && blockIdx.x == 0) {
        int off = 0, nt = 0;
        for (int e = 0; e < NE; e++) {
            offsets[e] = off;
            int c = counts[e];
            for (int s = 0; s < c; s += TMM) {
                tile_e[nt] = e;
                tile_s[nt] = off + s;
                tile_rows[nt] = min(TMM, c - s);
                nt++;
            }
            off += c;
        }
        offsets[NE] = off;
        *ntiles = nt;   // <= 4096/128 + 8 = 40

        float mean = 0.f;
        for (int e = 0; e < NE; e++) mean += importance[e];
        mean *= (1.0f / NE);
        float var = 0.f;
        for (int e = 0; e < NE; e++) { float d = importance[e] - mean; var += d * d; }
        var *= (1.0f / (NE - 1));
        loss_out[0] = var / (mean * mean + 1e-10f);
    }
}

// ---------------------------------------------------------------------------
// Scatter: sorted token list per expert.
// ---------------------------------------------------------------------------
__global__ void scatter_kernel(const int* __restrict__ top_idx,
                               const int* __restrict__ offsets,
                               int* __restrict__ cursors,
                               int* __restrict__ sorted_tok)
{
    int t = blockIdx.x * blockDim.x + threadIdx.x;
    if (t < T_TOK) {
        int e = top_idx[t];
        int pos = atomicAdd(&cursors[e], 1);
        sorted_tok[offsets[e] + pos] = t;
    }
}

// ---------------------------------------------------------------------------
// Gather x rows into sorted order, fp32 -> bf16. One block per sorted row.
// ---------------------------------------------------------------------------
__global__ __launch_bounds__(256) void gather_x_kernel(
    const float* __restrict__ x, const int* __restrict__ sorted_tok,
    u16* __restrict__ xs)
{
    const int s = blockIdx.x;
    const int tok = sorted_tok[s];
    const float* src = x + (size_t)tok * DIM;
    u16* dst = xs + (size_t)s * DIM;
    const int i = threadIdx.x * 4;
    float4 v = *(const float4*)&src[i];
    ushort4 o;
    o.x = f2bf(v.x); o.y = f2bf(v.y); o.z = f2bf(v.z); o.w = f2bf(v.w);
    *(ushort4*)&dst[i] = o;
}

// ---------------------------------------------------------------------------
// Transpose + convert: in [E][R][C] f32  ->  out [E][C][R] bf16
// 64x64 tiles; float4 loads, ushort4 stores (128B per 16 lanes).
// grid (C/64, R/64, E), block 256.
// ---------------------------------------------------------------------------
__global__ __launch_bounds__(256) void transpose_bf16_kernel(
    const float* __restrict__ in, u16* __restrict__ out, int R, int C)
{
    __shared__ float tile[64][65];
    const float* src = in  + (size_t)blockIdx.z * R * C;
    u16*         dst = out + (size_t)blockIdx.z * R * C;
    const int c0 = blockIdx.x * 64, r0 = blockIdx.y * 64;
    const int th = threadIdx.x;

    // load: thread -> rows (th>>4)+16i, cols (th&15)*4 .. +3
    const int tr  = th >> 4;
    const int tc4 = (th & 15) * 4;
    #pragma unroll
    for (int i = 0; i < 4; i++) {
        const int r = tr + i * 16;
        float4 v = *(const float4*)&src[(size_t)(r0 + r) * C + c0 + tc4];
        tile[r][tc4 + 0] = v.x; tile[r][tc4 + 1] = v.y;
        tile[r][tc4 + 2] = v.z; tile[r][tc4 + 3] = v.w;
    }
    __syncthreads();
    // store: thread -> out-row c0+(th>>4)+16i, r-offset (th&15)*4, ushort4
    const int cc  = th >> 4;
    const int rr4 = (th & 15) * 4;
    #pragma unroll
    for (int i = 0; i < 4; i++) {
        const int c = cc + i * 16;
        ushort4 o;
        o.x = f2bf(tile[rr4 + 0][c]);
        o.y = f2bf(tile[rr4 + 1][c]);
        o.z = f2bf(tile[rr4 + 2][c]);
        o.w = f2bf(tile[rr4 + 3][c]);
        *(ushort4*)&dst[(size_t)(c0 + c) * R + r0 + rr4] = o;
    }
}

// ---------------------------------------------------------------------------
// FFN1 (MFMA 16x16x32, single-buffer, 128x64 tile, XOR-swizzled LDS):
// h = gelu(Xs @ W1t^T + b1) in sorted order, bf16 out.
// Xs: [4096][DIM] bf16 (sorted). W1t: [E][HID][DIM] bf16. h: [4096][HID] bf16.
// Swizzle: lane l fetches global 16B-chunk (l&7)^(l>>3), so LDS[r][j] holds
// global chunk j^(r&7); fragment reads use chunk (ks*4+(l>>4))^(l&7) ->
// banks fully spread (2-way only, free per m136).
// ---------------------------------------------------------------------------
__global__ __launch_bounds__(256) void ffn1_mfma(
    const u16* __restrict__ xs, const u16* __restrict__ w1t,
    const float* __restrict__ b1,
    const int* __restrict__ tile_e, const int* __restrict__ tile_s,
    const int* __restrict__ tile_rows, const int* __restrict__ ntiles,
    u16* __restrict__ h_buf)
{
    const int tile = blockIdx.x;
    if (tile >= *ntiles) return;
    const int e     = tile_e[tile];
    const int sbase = tile_s[tile];
    const int rows  = tile_rows[tile];
    const int nbase = blockIdx.y * TNN;    // over HID

    __shared__ __align__(16) u16 As[TMM * BK];   // 16 KB
    __shared__ __align__(16) u16 Bs[TNN * BK];   // 8 KB

    const int th = threadIdx.x;
    const int w  = th >> 6;
    const int l  = th & 63;
    const int wm = w >> 1, wn = w & 1;
    const int lr = l >> 3;                  // 0..7 row in staging group
    const int lcs = ((l & 7) ^ lr) * 8;     // swizzled u16 fetch offset

    // A staging: 4 groups of 8 rows per wave (128 rows total)
    const u16* aptr[4];
    #pragma unroll
    for (int c = 0; c < 4; c++) {
        int srow = sbase + w * 32 + c * 8 + lr;
        if (srow > T_TOK - 1) srow = T_TOK - 1;
        aptr[c] = xs + (size_t)srow * DIM + lcs;
    }
    // B staging: 2 groups of 8 rows per wave (64 rows total)
    const u16* wb = w1t + (size_t)e * HID * DIM + (size_t)nbase * DIM;
    const u16* bptr[2];
    #pragma unroll
    for (int c = 0; c < 2; c++)
        bptr[c] = wb + (size_t)(w * 16 + c * 8 + lr) * DIM + lcs;

    f32x4 acc[4][2] = {};

    for (int k0 = 0; k0 < DIM; k0 += BK) {
        __syncthreads();
        #pragma unroll
        for (int c = 0; c < 4; c++)
            gld_lds16(aptr[c] + k0, &As[(w * 32 + c * 8) * BK]);
        #pragma unroll
        for (int c = 0; c < 2; c++)
            gld_lds16(bptr[c] + k0, &Bs[(w * 16 + c * 8) * BK]);
        __syncthreads();
        #pragma unroll
        for (int ks = 0; ks < 2; ks++) {
            const int ko = ((ks * 4 + (l >> 4)) ^ (l & 7)) * 8;  // swizzled chunk
            bf16x8 af[4], bfr[2];
            #pragma unroll
            for (int i = 0; i < 4; i++)
                af[i]  = *(const bf16x8*)&As[(wm * 64 + i * 16 + (l & 15)) * BK + ko];
            #pragma unroll
            for (int i = 0; i < 2; i++)
                bfr[i] = *(const bf16x8*)&Bs[(wn * 32 + i * 16 + (l & 15)) * BK + ko];
            #pragma unroll
            for (int mi = 0; mi < 4; mi++)
                #pragma unroll
                for (int ni = 0; ni < 2; ni++)
                    acc[mi][ni] = __builtin_amdgcn_mfma_f32_16x16x32_bf16(
                        af[mi], bfr[ni], acc[mi][ni], 0, 0, 0);
        }
    }

    const int col = l & 15, quad = l >> 4;
    #pragma unroll
    for (int ni = 0; ni < 2; ni++) {
        const int n = nbase + wn * 32 + ni * 16 + col;
        const float bias = b1[e * HID + n];
        #pragma unroll
        for (int mi = 0; mi < 4; mi++) {
            #pragma unroll
            for (int r = 0; r < 4; r++) {
                const int m = wm * 64 + mi * 16 + quad * 4 + r;
                if (m < rows) {
                    float v = acc[mi][ni][r] + bias;
                    h_buf[(size_t)(sbase + m) * HID + n] = f2bf(gelu_fast(v));
                }
            }
        }
    }
}

// ---------------------------------------------------------------------------
// FFN2 (MFMA 16x16x32, single-buffer, 128x64 tile, XOR-swizzled LDS):
// y = x + (h @ W2t^T + b2) * top_val, scattered to token order (fp32 out).
// ---------------------------------------------------------------------------
__global__ __launch_bounds__(256) void ffn2_mfma(
    const u16* __restrict__ h_buf, const u16* __restrict__ w2t,
    const float* __restrict__ b2, const float* __restrict__ x,
    const int* __restrict__ sorted_tok, const float* __restrict__ top_val,
    const int* __restrict__ tile_e, const int* __restrict__ tile_s,
    const int* __restrict__ tile_rows, const int* __restrict__ ntiles,
    float* __restrict__ yout)
{
    const int tile = blockIdx.x;
    if (tile >= *ntiles) return;
    const int e     = tile_e[tile];
    const int sbase = tile_s[tile];
    const int rows  = tile_rows[tile];
    const int nbase = blockIdx.y * TNN;    // over DIM

    __shared__ __align__(16) u16 As[TMM * BK];
    __shared__ __align__(16) u16 Bs[TNN * BK];

    const int th = threadIdx.x;
    const int w  = th >> 6;
    const int l  = th & 63;
    const int wm = w >> 1, wn = w & 1;
    const int lr = l >> 3;
    const int lcs = ((l & 7) ^ lr) * 8;

    const u16* aptr[4];
    #pragma unroll
    for (int c = 0; c < 4; c++) {
        int srow = sbase + w * 32 + c * 8 + lr;
        if (srow > T_TOK - 1) srow = T_TOK - 1;
        aptr[c] = h_buf + (size_t)srow * HID + lcs;
    }
    const u16* wb = w2t + (size_t)e * DIM * HID + (size_t)nbase * HID;
    const u16* bptr[2];
    #pragma unroll
    for (int c = 0; c < 2; c++)
        bptr[c] = wb + (size_t)(w * 16 + c * 8 + lr) * HID + lcs;

    f32x4 acc[4][2] = {};

    for (int k0 = 0; k0 < HID; k0 += BK) {
        __syncthreads();
        #pragma unroll
        for (int c = 0; c < 4; c++)
            gld_lds16(aptr[c] + k0, &As[(w * 32 + c * 8) * BK]);
        #pragma unroll
        for (int c = 0; c < 2; c++)
            gld_lds16(bptr[c] + k0, &Bs[(w * 16 + c * 8) * BK]);
        __syncthreads();
        #pragma unroll
        for (int ks = 0; ks < 2; ks++) {
            const int ko = ((ks * 4 + (l >> 4)) ^ (l & 7)) * 8;
            bf16x8 af[4], bfr[2];
            #pragma unroll
            for (int i = 0; i < 4; i++)
                af[i]  = *(const bf16x8*)&As[(wm * 64 + i * 16 + (l & 15)) * BK + ko];
            #pragma unroll
            for (int i = 0; i < 2; i++)
                bfr[i] = *(const bf16x8*)&Bs[(wn * 32 + i * 16 + (l & 15)) * BK + ko];
            #pragma unroll
            for (int mi = 0; mi < 4; mi++)
                #pragma unroll
                for (int ni = 0; ni < 2; ni++)
                    acc[mi][ni] = __builtin_amdgcn_mfma_f32_16x16x32_bf16(
                        af[mi], bfr[ni], acc[mi][ni], 0, 0, 0);
        }
    }

    const int col = l & 15, quad = l >> 4;
    float bias[2];
    #pragma unroll
    for (int ni = 0; ni < 2; ni++)
        bias[ni] = b2[e * DIM + nbase + wn * 32 + ni * 16 + col];

    #pragma unroll
    for (int mi = 0; mi < 4; mi++) {
        #pragma unroll
        for (int r = 0; r < 4; r++) {
            const int m = wm * 64 + mi * 16 + quad * 4 + r;
            if (m < rows) {
                const int t = sorted_tok[sbase + m];
                const float tv = top_val[t];
                #pragma unroll
                for (int ni = 0; ni < 2; ni++) {
                    const int n = nbase + wn * 32 + ni * 16 + col;
                    float v = acc[mi][ni][r] + bias[ni];
                    yout[(size_t)t * DIM + n] = x[(size_t)t * DIM + n] + v * tv;
                }
            }
        }
    }
}

// ---------------------------------------------------------------------------
// RMSNorm (F.normalize * gamma * sqrt(D)) + exact GeLU, in place.
// ---------------------------------------------------------------------------
__global__ __launch_bounds__(256) void norm_kernel(float* __restrict__ y,
                                                   const float* __restrict__ gamma)
{
    const int t = blockIdx.x;
    float* row = y + (size_t)t * DIM;
    const int th = threadIdx.x;
    float4 v = *(const float4*)&row[th * 4];
    float ss = v.x * v.x + v.y * v.y + v.z * v.z + v.w * v.w;

    const int lane = th & 63, wave = th >> 6;
    #pragma unroll
    for (int off = 32; off > 0; off >>= 1) ss += __shfl_down(ss, off, 64);
    __shared__ float red[4];
    if (lane == 0) red[wave] = ss;
    __syncthreads();
    float total = red[0] + red[1] + red[2] + red[3];

    float nrm = sqrtf(total);
    float scale = 32.0f / fmaxf(nrm, 1e-12f);   // sqrt(1024) = 32

    float4 g = *(const float4*)&gamma[th * 4];
    float4 o;
    o.x = gelu_exact(v.x * scale * g.x);
    o.y = gelu_exact(v.y * scale * g.y);
    o.z = gelu_exact(v.z * scale * g.z);
    o.w = gelu_exact(v.w * scale * g.w);
    *(float4*)&row[th * 4] = o;
}

// ---------------------------------------------------------------------------
extern "C" void kernel_launch(void* const* d_in, const int* in_sizes, int n_in,
                              void* d_out, int out_size, void* d_ws, size_t ws_size,
                              hipStream_t stream) {
    const float* x      = (const float*)d_in[0];
    const float* gate_w = (const float*)d_in[1];
    const float* gate_b = (const float*)d_in[2];
    const float* w1     = (const float*)d_in[3];
    const float* b1     = (const float*)d_in[4];
    const float* w2     = (const float*)d_in[5];
    const float* b2     = (const float*)d_in[6];
    const float* gamma  = (const float*)d_in[7];

    float* out  = (float*)d_out;                  // [T*D] y, then [1] loss
    float* loss = out + (size_t)T_TOK * DIM;

    char* ws = (char*)d_ws;
    float* top_val    = (float*)(ws + 0);         // 4096 f
    int*   top_idx    = (int*)  (ws + 16384);     // 4096 i
    int*   sorted_tok = (int*)  (ws + 32768);     // 4096 i
    float* importance = (float*)(ws + 49152);     // 8 f  (zeroed)
    int*   counts     = (int*)  (ws + 49184);     // 8 i  (zeroed)
    int*   cursors    = (int*)  (ws + 49216);     // 8 i  (zeroed)
    int*   offsets    = (int*)  (ws + 49248);     // 9 i
    int*   tile_e     = (int*)  (ws + 49536);     // 40 i
    int*   tile_s     = (int*)  (ws + 49824);     // 40 i
    int*   tile_rows  = (int*)  (ws + 50112);     // 40 i
    int*   ntiles     = (int*)  (ws + 50400);     // 1 i
    u16*   x_sorted   = (u16*)  (ws + 65536);                    // 8 MiB
    u16*   h_buf      = (u16*)  (ws + 65536 + 8388608);          // 16 MiB
    u16*   w1t        = (u16*)  (ws + 65536 + 8388608 + 16777216);            // 32 MiB
    u16*   w2t        = (u16*)  (ws + 65536 + 8388608 + 16777216 + 33554432); // 32 MiB

    hipMemsetAsync(ws + 49152, 0, 96, stream);

    gate_kernel<<<T_TOK / 4, 256, 0, stream>>>(x, gate_w, gate_b, top_val,
                                               top_idx, importance, counts);
    plan_kernel<<<1, 64, 0, stream>>>(counts, importance, offsets, tile_e,
                                      tile_s, tile_rows, ntiles, loss);
    scatter_kernel<<<T_TOK / 256, 256, 0, stream>>>(top_idx, offsets, cursors,
                                                    sorted_tok);
    gather_x_kernel<<<T_TOK, 256, 0, stream>>>(x, sorted_tok, x_sorted);
    // w1 [E][D][H] -> w1t [E][H][D]   (R=DIM, C=HID)
    transpose_bf16_kernel<<<dim3(HID / 64, DIM / 64, NE), 256, 0, stream>>>(
        w1, w1t, DIM, HID);
    // w2 [E][H][D] -> w2t [E][D][H]   (R=HID, C=DIM)
    transpose_bf16_kernel<<<dim3(DIM / 64, HID / 64, NE), 256, 0, stream>>>(
        w2, w2t, HID, DIM);

    ffn1_mfma<<<dim3(40, HID / TNN), 256, 0, stream>>>(
        x_sorted, w1t, b1, tile_e, tile_s, tile_rows, ntiles, h_buf);
    ffn2_mfma<<<dim3(40, DIM / TNN), 256, 0, stream>>>(
        h_buf, w2t, b2, x, sorted_tok, top_val, tile_e, tile_s, tile_rows,
        ntiles, out);
    norm_kernel<<<T_TOK, 256, 0, stream>>>(out, gamma);
}

// Round 6
// 298.226 us; speedup vs baseline: 1.5182x; 1.1220x over previous
//
#include <hip/hip_runtime.h>
#include <math.h>

// Problem constants (B=4, N=1024, D=1024, H=2048, E=8)
#define T_TOK 4096
#define DIM   1024
#define HID   2048
#define NE    8
#define TMM   128   // M tile (tokens)
#define TNN   64    // N tile
#define BK    64    // K chunk (bf16)
#define GATE_BLOCKS (T_TOK / 4)

typedef unsigned int  u32;
typedef unsigned short u16;
typedef __attribute__((ext_vector_type(8))) short bf16x8;  // 8 bf16 in 4 VGPRs
typedef __attribute__((ext_vector_type(4))) float f32x4;

__device__ __forceinline__ float gelu_exact(float v) {
    return 0.5f * v * (1.0f + erff(v * 0.70710678118654752440f));
}

// tanh-form gelu: max abs err vs exact ~1e-3; one v_exp instead of erff poly
__device__ __forceinline__ float gelu_fast(float x) {
    float u = 1.5957691216057308f * (x + 0.044715f * x * x * x); // 2*0.79788456
    float e = __expf(u);                  // exp(2u')
    float t = 1.f - 2.f / (e + 1.f);      // tanh(u')
    return 0.5f * x * (1.f + t);
}

__device__ __forceinline__ u16 f2bf(float v) {
    u32 u = __float_as_uint(v);
    u32 r = (u + 0x7FFFu + ((u >> 16) & 1u)) >> 16;   // RNE
    return (u16)r;
}

// async global->LDS, 16B per lane; lds dest = wave-uniform base + lane*16
__device__ __forceinline__ void gld_lds16(const void* g, void* l) {
    __builtin_amdgcn_global_load_lds(
        (const __attribute__((address_space(1))) u32*)g,
        (__attribute__((address_space(3))) u32*)l,
        16, 0, 0);
}

// ---------------------------------------------------------------------------
// Gate: logits = x @ gate_w + gate_b ; softmax ; top-1.
// Per-block partial importance/count -> plain stores (NO global atomics).
// ---------------------------------------------------------------------------
__global__ __launch_bounds__(256) void gate_kernel(
    const float* __restrict__ x, const float* __restrict__ gw,
    const float* __restrict__ gb, float* __restrict__ top_val,
    int* __restrict__ top_idx, float* __restrict__ partial_imp,
    int* __restrict__ partial_cnt)
{
    __shared__ float s_imp[NE];
    __shared__ int   s_cnt[NE];
    if (threadIdx.x < NE) { s_imp[threadIdx.x] = 0.f; s_cnt[threadIdx.x] = 0; }
    __syncthreads();

    const int wave = threadIdx.x >> 6;
    const int lane = threadIdx.x & 63;
    const int t = blockIdx.x * 4 + wave;

    float acc[NE];
    #pragma unroll
    for (int e = 0; e < NE; e++) acc[e] = 0.f;

    const float* xr = x + (size_t)t * DIM;
    #pragma unroll 4
    for (int k = lane; k < DIM; k += 64) {
        float xv = xr[k];
        const float* g = gw + (size_t)k * NE;
        float4 g0 = *(const float4*)g;
        float4 g1 = *(const float4*)(g + 4);
        acc[0] += xv * g0.x; acc[1] += xv * g0.y;
        acc[2] += xv * g0.z; acc[3] += xv * g0.w;
        acc[4] += xv * g1.x; acc[5] += xv * g1.y;
        acc[6] += xv * g1.z; acc[7] += xv * g1.w;
    }
    #pragma unroll
    for (int e = 0; e < NE; e++) {
        #pragma unroll
        for (int off = 32; off > 0; off >>= 1)
            acc[e] += __shfl_down(acc[e], off, 64);
    }
    if (lane == 0) {
        float l[NE];
        float m = -1e30f;
        #pragma unroll
        for (int e = 0; e < NE; e++) { l[e] = acc[e] + gb[e]; m = fmaxf(m, l[e]); }
        float s = 0.f;
        #pragma unroll
        for (int e = 0; e < NE; e++) { l[e] = expf(l[e] - m); s += l[e]; }
        float inv = 1.f / s;
        int bi = 0; float bv = -1.f;
        #pragma unroll
        for (int e = 0; e < NE; e++) {
            float p = l[e] * inv;
            atomicAdd(&s_imp[e], p);             // LDS atomic: cheap
            if (p > bv) { bv = p; bi = e; }      // strict > => first argmax
        }
        top_val[t] = bv;
        top_idx[t] = bi;
        atomicAdd(&s_cnt[bi], 1);
    }
    __syncthreads();
    if (threadIdx.x < NE) {
        partial_imp[blockIdx.x * NE + threadIdx.x] = s_imp[threadIdx.x];
        partial_cnt[blockIdx.x * NE + threadIdx.x] = s_cnt[threadIdx.x];
    }
}

// ---------------------------------------------------------------------------
// Plan (1 block, 256 thr): reduce partials -> counts/importance; build
// offsets + 128-row tile table; load-balance loss. No serialized global RMW.
// ---------------------------------------------------------------------------
__global__ __launch_bounds__(256) void plan_kernel(
    const float* __restrict__ partial_imp, const int* __restrict__ partial_cnt,
    int* __restrict__ counts, int* __restrict__ offsets,
    int* __restrict__ tile_e, int* __restrict__ tile_s,
    int* __restrict__ tile_rows, int* __restrict__ ntiles,
    float* __restrict__ loss_out)
{
    __shared__ float rimp[32][NE];
    __shared__ int   rcnt[32][NE];
    const int th = threadIdx.x;
    const int e = th & 7, chunk = th >> 3;   // 32 chunks of 32 blocks
    float si = 0.f; int sc = 0;
    #pragma unroll 8
    for (int i = 0; i < GATE_BLOCKS / 32; i++) {
        const int b = chunk * (GATE_BLOCKS / 32) + i;
        si += partial_imp[b * NE + e];
        sc += partial_cnt[b * NE + e];
    }
    rimp[chunk][e] = si;
    rcnt[chunk][e] = sc;
    __syncthreads();
    if (th < NE) {
        float s = 0.f; int c = 0;
        for (int i = 0; i < 32; i++) { s += rimp[i][th]; c += rcnt[i][th]; }
        counts[th] = c;
        rimp[0][th] = s;
        rcnt[0][th] = c;
    }
    __syncthreads();
    if (th == 0) {
        int off = 0, nt = 0;
        for (int ee = 0; ee < NE; ee++) {
            offsets[ee] = off;
            const int c = rcnt[0][ee];
            for (int s = 0; s < c; s += TMM) {
                tile_e[nt] = ee;
                tile_s[nt] = off + s;
                tile_rows[nt] = min(TMM, c - s);
                nt++;
            }
            off += c;
        }
        offsets[NE] = off;
        *ntiles = nt;   // <= 4096/128 + 8 = 40

        float mean = 0.f;
        for (int ee = 0; ee < NE; ee++) mean += rimp[0][ee];
        mean *= (1.0f / NE);
        float var = 0.f;
        for (int ee = 0; ee < NE; ee++) { float d = rimp[0][ee] - mean; var += d * d; }
        var *= (1.0f / (NE - 1));
        loss_out[0] = var / (mean * mean + 1e-10f);
    }
}

// ---------------------------------------------------------------------------
// Scatter: sorted token list per expert. LDS-aggregated ranks ->
// 8 global atomics per block instead of 256.
// ---------------------------------------------------------------------------
__global__ __launch_bounds__(256) void scatter_kernel(
    const int* __restrict__ top_idx, const int* __restrict__ offsets,
    int* __restrict__ cursors, int* __restrict__ sorted_tok)
{
    __shared__ int lcnt[NE], lbase[NE];
    if (threadIdx.x < NE) lcnt[threadIdx.x] = 0;
    __syncthreads();
    const int t = blockIdx.x * blockDim.x + threadIdx.x;   // T_TOK % 256 == 0
    const int e = top_idx[t];
    const int lrank = atomicAdd(&lcnt[e], 1);
    __syncthreads();
    if (threadIdx.x < NE)
        lbase[threadIdx.x] = atomicAdd(&cursors[threadIdx.x], lcnt[threadIdx.x]);
    __syncthreads();
    sorted_tok[offsets[e] + lbase[e] + lrank] = t;
}

// ---------------------------------------------------------------------------
// Gather x rows into sorted order, fp32 -> bf16. One block per sorted row.
// ---------------------------------------------------------------------------
__global__ __launch_bounds__(256) void gather_x_kernel(
    const float* __restrict__ x, const int* __restrict__ sorted_tok,
    u16* __restrict__ xs)
{
    const int s = blockIdx.x;
    const int tok = sorted_tok[s];
    const float* src = x + (size_t)tok * DIM;
    u16* dst = xs + (size_t)s * DIM;
    const int i = threadIdx.x * 4;
    float4 v = *(const float4*)&src[i];
    ushort4 o;
    o.x = f2bf(v.x); o.y = f2bf(v.y); o.z = f2bf(v.z); o.w = f2bf(v.w);
    *(ushort4*)&dst[i] = o;
}

// ---------------------------------------------------------------------------
// Transpose + convert: in [E][R][C] f32  ->  out [E][C][R] bf16
// 64x64 tiles; float4 loads, ushort4 stores (128B per 16 lanes).
// grid (C/64, R/64, E), block 256.
// ---------------------------------------------------------------------------
__global__ __launch_bounds__(256) void transpose_bf16_kernel(
    const float* __restrict__ in, u16* __restrict__ out, int R, int C)
{
    __shared__ float tile[64][65];
    const float* src = in  + (size_t)blockIdx.z * R * C;
    u16*         dst = out + (size_t)blockIdx.z * R * C;
    const int c0 = blockIdx.x * 64, r0 = blockIdx.y * 64;
    const int th = threadIdx.x;

    const int tr  = th >> 4;
    const int tc4 = (th & 15) * 4;
    #pragma unroll
    for (int i = 0; i < 4; i++) {
        const int r = tr + i * 16;
        float4 v = *(const float4*)&src[(size_t)(r0 + r) * C + c0 + tc4];
        tile[r][tc4 + 0] = v.x; tile[r][tc4 + 1] = v.y;
        tile[r][tc4 + 2] = v.z; tile[r][tc4 + 3] = v.w;
    }
    __syncthreads();
    const int cc  = th >> 4;
    const int rr4 = (th & 15) * 4;
    #pragma unroll
    for (int i = 0; i < 4; i++) {
        const int c = cc + i * 16;
        ushort4 o;
        o.x = f2bf(tile[rr4 + 0][c]);
        o.y = f2bf(tile[rr4 + 1][c]);
        o.z = f2bf(tile[rr4 + 2][c]);
        o.w = f2bf(tile[rr4 + 3][c]);
        *(ushort4*)&dst[(size_t)(c0 + c) * R + r0 + rr4] = o;
    }
}

// ---------------------------------------------------------------------------
// FFN1 (MFMA 16x16x32, single-buffer, 128x64 tile, XOR-swizzled LDS):
// h = gelu(Xs @ W1t^T + b1) in sorted order, bf16 out.
// Swizzle: lane l fetches global 16B-chunk (l&7)^(l>>3); fragment reads use
// chunk (ks*4+(l>>4))^(l&7) -> banks fully spread (conflicts measured 0).
// ---------------------------------------------------------------------------
__global__ __launch_bounds__(256) void ffn1_mfma(
    const u16* __restrict__ xs, const u16* __restrict__ w1t,
    const float* __restrict__ b1,
    const int* __restrict__ tile_e, const int* __restrict__ tile_s,
    const int* __restrict__ tile_rows, const int* __restrict__ ntiles,
    u16* __restrict__ h_buf)
{
    const int tile = blockIdx.x;
    if (tile >= *ntiles) return;
    const int e     = tile_e[tile];
    const int sbase = tile_s[tile];
    const int rows  = tile_rows[tile];
    const int nbase = blockIdx.y * TNN;    // over HID

    __shared__ __align__(16) u16 As[TMM * BK];   // 16 KB
    __shared__ __align__(16) u16 Bs[TNN * BK];   // 8 KB

    const int th = threadIdx.x;
    const int w  = th >> 6;
    const int l  = th & 63;
    const int wm = w >> 1, wn = w & 1;
    const int lr = l >> 3;                  // 0..7 row in staging group
    const int lcs = ((l & 7) ^ lr) * 8;     // swizzled u16 fetch offset

    const u16* aptr[4];
    #pragma unroll
    for (int c = 0; c < 4; c++) {
        int srow = sbase + w * 32 + c * 8 + lr;
        if (srow > T_TOK - 1) srow = T_TOK - 1;
        aptr[c] = xs + (size_t)srow * DIM + lcs;
    }
    const u16* wb = w1t + (size_t)e * HID * DIM + (size_t)nbase * DIM;
    const u16* bptr[2];
    #pragma unroll
    for (int c = 0; c < 2; c++)
        bptr[c] = wb + (size_t)(w * 16 + c * 8 + lr) * DIM + lcs;

    f32x4 acc[4][2] = {};

    for (int k0 = 0; k0 < DIM; k0 += BK) {
        __syncthreads();
        #pragma unroll
        for (int c = 0; c < 4; c++)
            gld_lds16(aptr[c] + k0, &As[(w * 32 + c * 8) * BK]);
        #pragma unroll
        for (int c = 0; c < 2; c++)
            gld_lds16(bptr[c] + k0, &Bs[(w * 16 + c * 8) * BK]);
        __syncthreads();
        #pragma unroll
        for (int ks = 0; ks < 2; ks++) {
            const int ko = ((ks * 4 + (l >> 4)) ^ (l & 7)) * 8;  // swizzled chunk
            bf16x8 af[4], bfr[2];
            #pragma unroll
            for (int i = 0; i < 4; i++)
                af[i]  = *(const bf16x8*)&As[(wm * 64 + i * 16 + (l & 15)) * BK + ko];
            #pragma unroll
            for (int i = 0; i < 2; i++)
                bfr[i] = *(const bf16x8*)&Bs[(wn * 32 + i * 16 + (l & 15)) * BK + ko];
            #pragma unroll
            for (int mi = 0; mi < 4; mi++)
                #pragma unroll
                for (int ni = 0; ni < 2; ni++)
                    acc[mi][ni] = __builtin_amdgcn_mfma_f32_16x16x32_bf16(
                        af[mi], bfr[ni], acc[mi][ni], 0, 0, 0);
        }
    }

    const int col = l & 15, quad = l >> 4;
    #pragma unroll
    for (int ni = 0; ni < 2; ni++) {
        const int n = nbase + wn * 32 + ni * 16 + col;
        const float bias = b1[e * HID + n];
        #pragma unroll
        for (int mi = 0; mi < 4; mi++) {
            #pragma unroll
            for (int r = 0; r < 4; r++) {
                const int m = wm * 64 + mi * 16 + quad * 4 + r;
                if (m < rows) {
                    float v = acc[mi][ni][r] + bias;
                    h_buf[(size_t)(sbase + m) * HID + n] = f2bf(gelu_fast(v));
                }
            }
        }
    }
}

// ---------------------------------------------------------------------------
// FFN2 (MFMA 16x16x32, single-buffer, 128x64 tile, XOR-swizzled LDS):
// y = x + (h @ W2t^T + b2) * top_val, scattered to token order (fp32 out).
// ---------------------------------------------------------------------------
__global__ __launch_bounds__(256) void ffn2_mfma(
    const u16* __restrict__ h_buf, const u16* __restrict__ w2t,
    const float* __restrict__ b2, const float* __restrict__ x,
    const int* __restrict__ sorted_tok, const float* __restrict__ top_val,
    const int* __restrict__ tile_e, const int* __restrict__ tile_s,
    const int* __restrict__ tile_rows, const int* __restrict__ ntiles,
    float* __restrict__ yout)
{
    const int tile = blockIdx.x;
    if (tile >= *ntiles) return;
    const int e     = tile_e[tile];
    const int sbase = tile_s[tile];
    const int rows  = tile_rows[tile];
    const int nbase = blockIdx.y * TNN;    // over DIM

    __shared__ __align__(16) u16 As[TMM * BK];
    __shared__ __align__(16) u16 Bs[TNN * BK];

    const int th = threadIdx.x;
    const int w  = th >> 6;
    const int l  = th & 63;
    const int wm = w >> 1, wn = w & 1;
    const int lr = l >> 3;
    const int lcs = ((l & 7) ^ lr) * 8;

    const u16* aptr[4];
    #pragma unroll
    for (int c = 0; c < 4; c++) {
        int srow = sbase + w * 32 + c * 8 + lr;
        if (srow > T_TOK - 1) srow = T_TOK - 1;
        aptr[c] = h_buf + (size_t)srow * HID + lcs;
    }
    const u16* wb = w2t + (size_t)e * DIM * HID + (size_t)nbase * HID;
    const u16* bptr[2];
    #pragma unroll
    for (int c = 0; c < 2; c++)
        bptr[c] = wb + (size_t)(w * 16 + c * 8 + lr) * HID + lcs;

    f32x4 acc[4][2] = {};

    for (int k0 = 0; k0 < HID; k0 += BK) {
        __syncthreads();
        #pragma unroll
        for (int c = 0; c < 4; c++)
            gld_lds16(aptr[c] + k0, &As[(w * 32 + c * 8) * BK]);
        #pragma unroll
        for (int c = 0; c < 2; c++)
            gld_lds16(bptr[c] + k0, &Bs[(w * 16 + c * 8) * BK]);
        __syncthreads();
        #pragma unroll
        for (int ks = 0; ks < 2; ks++) {
            const int ko = ((ks * 4 + (l >> 4)) ^ (l & 7)) * 8;
            bf16x8 af[4], bfr[2];
            #pragma unroll
            for (int i = 0; i < 4; i++)
                af[i]  = *(const bf16x8*)&As[(wm * 64 + i * 16 + (l & 15)) * BK + ko];
            #pragma unroll
            for (int i = 0; i < 2; i++)
                bfr[i] = *(const bf16x8*)&Bs[(wn * 32 + i * 16 + (l & 15)) * BK + ko];
            #pragma unroll
            for (int mi = 0; mi < 4; mi++)
                #pragma unroll
                for (int ni = 0; ni < 2; ni++)
                    acc[mi][ni] = __builtin_amdgcn_mfma_f32_16x16x32_bf16(
                        af[mi], bfr[ni], acc[mi][ni], 0, 0, 0);
        }
    }

    const int col = l & 15, quad = l >> 4;
    float bias[2];
    #pragma unroll
    for (int ni = 0; ni < 2; ni++)
        bias[ni] = b2[e * DIM + nbase + wn * 32 + ni * 16 + col];

    #pragma unroll
    for (int mi = 0; mi < 4; mi++) {
        #pragma unroll
        for (int r = 0; r < 4; r++) {
            const int m = wm * 64 + mi * 16 + quad * 4 + r;
            if (m < rows) {
                const int t = sorted_tok[sbase + m];
                const float tv = top_val[t];
                #pragma unroll
                for (int ni = 0; ni < 2; ni++) {
                    const int n = nbase + wn * 32 + ni * 16 + col;
                    float v = acc[mi][ni][r] + bias[ni];
                    yout[(size_t)t * DIM + n] = x[(size_t)t * DIM + n] + v * tv;
                }
            }
        }
    }
}

// ---------------------------------------------------------------------------
// RMSNorm (F.normalize * gamma * sqrt(D)) + exact GeLU, in place.
// ---------------------------------------------------------------------------
__global__ __launch_bounds__(256) void norm_kernel(float* __restrict__ y,
                                                   const float* __restrict__ gamma)
{
    const int t = blockIdx.x;
    float* row = y + (size_t)t * DIM;
    const int th = threadIdx.x;
    float4 v = *(const float4*)&row[th * 4];
    float ss = v.x * v.x + v.y * v.y + v.z * v.z + v.w * v.w;

    const int lane = th & 63, wave = th >> 6;
    #pragma unroll
    for (int off = 32; off > 0; off >>= 1) ss += __shfl_down(ss, off, 64);
    __shared__ float red[4];
    if (lane == 0) red[wave] = ss;
    __syncthreads();
    float total = red[0] + red[1] + red[2] + red[3];

    float nrm = sqrtf(total);
    float scale = 32.0f / fmaxf(nrm, 1e-12f);   // sqrt(1024) = 32

    float4 g = *(const float4*)&gamma[th * 4];
    float4 o;
    o.x = gelu_exact(v.x * scale * g.x);
    o.y = gelu_exact(v.y * scale * g.y);
    o.z = gelu_exact(v.z * scale * g.z);
    o.w = gelu_exact(v.w * scale * g.w);
    *(float4*)&row[th * 4] = o;
}

// ---------------------------------------------------------------------------
extern "C" void kernel_launch(void* const* d_in, const int* in_sizes, int n_in,
                              void* d_out, int out_size, void* d_ws, size_t ws_size,
                              hipStream_t stream) {
    const float* x      = (const float*)d_in[0];
    const float* gate_w = (const float*)d_in[1];
    const float* gate_b = (const float*)d_in[2];
    const float* w1     = (const float*)d_in[3];
    const float* b1     = (const float*)d_in[4];
    const float* w2     = (const float*)d_in[5];
    const float* b2     = (const float*)d_in[6];
    const float* gamma  = (const float*)d_in[7];

    float* out  = (float*)d_out;                  // [T*D] y, then [1] loss
    float* loss = out + (size_t)T_TOK * DIM;

    char* ws = (char*)d_ws;
    float* top_val     = (float*)(ws + 0);         // 4096 f
    int*   top_idx     = (int*)  (ws + 16384);     // 4096 i
    int*   sorted_tok  = (int*)  (ws + 32768);     // 4096 i
    int*   counts      = (int*)  (ws + 49152);     // 8 i
    int*   cursors     = (int*)  (ws + 49216);     // 8 i  (zeroed)
    int*   offsets     = (int*)  (ws + 49280);     // 9 i
    int*   tile_e      = (int*)  (ws + 49664);     // 40 i
    int*   tile_s      = (int*)  (ws + 50176);     // 40 i
    int*   tile_rows   = (int*)  (ws + 50688);     // 40 i
    int*   ntiles      = (int*)  (ws + 51200);     // 1 i
    float* partial_imp = (float*)(ws + 65536);     // 1024*8 f = 32 KB
    int*   partial_cnt = (int*)  (ws + 98304);     // 1024*8 i = 32 KB
    u16*   x_sorted    = (u16*)  (ws + 131072);                      // 8 MiB
    u16*   h_buf       = (u16*)  (ws + 131072 + 8388608);            // 16 MiB
    u16*   w1t         = (u16*)  (ws + 131072 + 8388608 + 16777216);            // 32 MiB
    u16*   w2t         = (u16*)  (ws + 131072 + 8388608 + 16777216 + 33554432); // 32 MiB

    hipMemsetAsync(ws + 49216, 0, 64, stream);     // cursors only

    gate_kernel<<<GATE_BLOCKS, 256, 0, stream>>>(x, gate_w, gate_b, top_val,
                                                 top_idx, partial_imp,
                                                 partial_cnt);
    plan_kernel<<<1, 256, 0, stream>>>(partial_imp, partial_cnt, counts,
                                       offsets, tile_e, tile_s, tile_rows,
                                       ntiles, loss);
    scatter_kernel<<<T_TOK / 256, 256, 0, stream>>>(top_idx, offsets, cursors,
                                                    sorted_tok);
    gather_x_kernel<<<T_TOK, 256, 0, stream>>>(x, sorted_tok, x_sorted);
    // w1 [E][D][H] -> w1t [E][H][D]   (R=DIM, C=HID)
    transpose_bf16_kernel<<<dim3(HID / 64, DIM / 64, NE), 256, 0, stream>>>(
        w1, w1t, DIM, HID);
    // w2 [E][H][D] -> w2t [E][D][H]   (R=HID, C=DIM)
    transpose_bf16_kernel<<<dim3(DIM / 64, HID / 64, NE), 256, 0, stream>>>(
        w2, w2t, HID, DIM);

    ffn1_mfma<<<dim3(40, HID / TNN), 256, 0, stream>>>(
        x_sorted, w1t, b1, tile_e, tile_s, tile_rows, ntiles, h_buf);
    ffn2_mfma<<<dim3(40, DIM / TNN), 256, 0, stream>>>(
        h_buf, w2t, b2, x, sorted_tok, top_val, tile_e, tile_s, tile_rows,
        ntiles, out);
    norm_kernel<<<T_TOK, 256, 0, stream>>>(out, gamma);
}